// Round 1
// 106.790 us; speedup vs baseline: 1.0887x; 1.0887x over previous
//
#include <hip/hip_runtime.h>
#include <hip/hip_bf16.h>

#define NNODE 512
#define CCH   16
#define TT    15
#define TP    16
#define HH    32
#define DD    32

typedef unsigned short u16;
typedef unsigned int   u32;
typedef short bf8 __attribute__((ext_vector_type(8)));   // 8 bf16 = 4 VGPR (MFMA A/B frag)
typedef float f4  __attribute__((ext_vector_type(4)));   // MFMA C/D frag

__device__ __forceinline__ float bf2f(u16 v) {
    union { u32 u; float f; } x; x.u = ((u32)v) << 16; return x.f;
}
__device__ __forceinline__ u16 f2bf(float f) {
    union { float f; u32 u; } x; x.f = f;
    u32 u = x.u;
    return (u16)((u + 0x7FFFu + ((u >> 16) & 1u)) >> 16);
}
__device__ __forceinline__ void unpack8(uint4 p, float* o) {
    o[0]=bf2f((u16)(p.x & 0xffffu)); o[1]=bf2f((u16)(p.x >> 16));
    o[2]=bf2f((u16)(p.y & 0xffffu)); o[3]=bf2f((u16)(p.y >> 16));
    o[4]=bf2f((u16)(p.z & 0xffffu)); o[5]=bf2f((u16)(p.z >> 16));
    o[6]=bf2f((u16)(p.w & 0xffffu)); o[7]=bf2f((u16)(p.w >> 16));
}
__device__ __forceinline__ uint4 pack8(const u16* v) {
    return make_uint4((u32)v[0]|((u32)v[1]<<16), (u32)v[2]|((u32)v[3]<<16),
                      (u32)v[4]|((u32)v[5]<<16), (u32)v[6]|((u32)v[7]<<16));
}

// ---------------------------------------------------------------------------
// K1: blocks 0..511: per-node prep: A1/B1 bf16 [n][t*32+h], Qb bf16,
//     QAd/QB f32, A2T/B2T [d][(k=n)*16+t] via coalesced u32 stores.
//     blocks 512..767: 32x32 adjacency tiles -> adjP[n][m*16+t] AND
//     adjPT[m][n*16+t] (bf16, diag folded into t=15).
// ---------------------------------------------------------------------------
__global__ __launch_bounds__(256) void k_prep_adjp(
    const float* __restrict__ x, const float* __restrict__ W1,
    const float* __restrict__ W2, const float* __restrict__ W3,
    const float* __restrict__ adj,
    u16* __restrict__ A1, u16* __restrict__ B1,
    u16* __restrict__ A2T, u16* __restrict__ B2T,
    u16* __restrict__ Qb, float* __restrict__ QAd, float* __restrict__ QB,
    u16* __restrict__ adjP, u16* __restrict__ adjPT)
{
    int tid = threadIdx.x;
    if (blockIdx.x < 512) {
        int n = blockIdx.x;
        __shared__ alignas(16) float xs[CCH];
        __shared__ alignas(16) float A1row[512], B1row[512];
        __shared__ alignas(16) float A2row[512], B2row[512];
        __shared__ alignas(16) float Qs[HH];
        if (tid < CCH) xs[tid] = x[n*CCH + tid];
        __syncthreads();
        float xr[CCH];
        #pragma unroll
        for (int i=0;i<CCH;i++) xr[i]=xs[i];
        #pragma unroll
        for (int rep=0; rep<2; rep++) {
            int c = tid + rep*256;
            float a1=0.f,b1=0.f,a2=0.f,b2=0.f;
            #pragma unroll
            for (int i=0;i<CCH;i++) {
                a1 += xr[i]*W1[i*512 + c];
                b1 += xr[i]*W1[(CCH+i)*512 + c];
                a2 += xr[i]*W2[i*512 + c];
                b2 += xr[i]*W2[(CCH+i)*512 + c];
            }
            A1[(size_t)n*512 + c]=f2bf(a1); B1[(size_t)n*512 + c]=f2bf(b1);
            A1row[c]=a1; B1row[c]=b1; A2row[c]=a2; B2row[c]=b2;
        }
        if (tid < HH) {
            float q=0.f;
            #pragma unroll
            for (int i=0;i<CCH;i++) q += xr[i]*W3[i*HH + tid];
            Qs[tid]=q; Qb[(size_t)n*HH + tid]=f2bf(q);
        }
        __syncthreads();
        if (tid < TP) {
            float qa=0.f, qb=0.f;
            #pragma unroll
            for (int h=0;h<HH;h++) { qa += Qs[h]*A1row[tid*HH+h]; qb += Qs[h]*B1row[tid*HH+h]; }
            QAd[(size_t)n*TP + tid]=qa; QB[(size_t)n*TP + tid]=qb;
        }
        {   // A2T/B2T: [d][n*16+t]; coalesced u32 stores
            int d = tid >> 3, t0 = (tid & 7) * 2;
            u32 pa = (u32)f2bf(A2row[t0*32 + d]) | ((u32)f2bf(A2row[(t0+1)*32 + d]) << 16);
            u32 pb = (u32)f2bf(B2row[t0*32 + d]) | ((u32)f2bf(B2row[(t0+1)*32 + d]) << 16);
            *(u32*)(A2T + (size_t)d*8192 + n*16 + t0) = pa;
            *(u32*)(B2T + (size_t)d*8192 + n*16 + t0) = pb;
        }
    } else {
        int b = blockIdx.x - 512;            // 0..255
        int n0 = (b >> 4) * 32, m0 = (b & 15) * 32;
        __shared__ alignas(16) u16 s[32*520];  // stride 520 (1040B=65*16)
        #pragma unroll
        for (int i = 0; i < 60; i++) {
            int e = tid + i*256;
            int nl = e / 480; int rem = e - nl*480;
            int ml = rem / 15; int t = rem - ml*15;
            float v = adj[((size_t)(n0+nl)*512 + (m0+ml))*TT + t];
            s[nl*520 + ml*16 + t] = f2bf(v);
        }
        #pragma unroll
        for (int i = 0; i < 4; i++) {
            int e = tid + i*256; int nl = e >> 5, ml = e & 31;
            s[nl*520 + ml*16 + 15] = ((n0+nl) == (m0+ml)) ? (u16)0x3F80 : (u16)0;
        }
        __syncthreads();
        #pragma unroll
        for (int i = 0; i < 8; i++) {        // adjP: 32 rows x 1KB
            int c = tid + i*256;
            int nl = c >> 6, off = (c & 63) * 8;
            uint4 vv = *(const uint4*)(s + nl*520 + off);
            *(uint4*)(adjP + (size_t)(n0+nl)*8192 + m0*16 + off) = vv;
        }
        #pragma unroll
        for (int i = 0; i < 8; i++) {        // adjPT: 32 rows x 1KB (transposed)
            int c = tid + i*256;
            int ml = c >> 6, nlh = c & 63, nl = nlh >> 1, half = nlh & 1;
            uint4 vv = *(const uint4*)(s + nl*520 + ml*16 + half*8);
            *(uint4*)(adjPT + (size_t)(m0+ml)*8192 + (n0+nl)*16 + half*8) = vv;
        }
    }
}

// ---------------------------------------------------------------------------
// K2: fused logits. Swapped-operand MFMA delivers G/H as D[t][col] so each
// lane owns 4 consecutive t's in registers (quad = t>>2): the t-reduction is
// 8 in-lane FMAs + 2 cross-quad shuffles (was 4-step shuffle per output),
// and the adjacency factors load as one coalesced 8B uint2 per lane.
// ---------------------------------------------------------------------------
__global__ __launch_bounds__(256) void k_logits(
    const u16* __restrict__ Qb, const u16* __restrict__ A1, const u16* __restrict__ B1,
    const u16* __restrict__ adjP, const u16* __restrict__ adjPT,
    const float* __restrict__ QAd, const float* __restrict__ QB,
    float* __restrict__ L1, float* __restrict__ L2T)
{
    const int m0 = blockIdx.x * 16, n0 = blockIdx.y * 16;
    const int tid = threadIdx.x;
    const int wv = tid >> 6, lane = tid & 63, l15 = lane & 15, quad = lane >> 4;
    __shared__ alignas(16) float sL1[16*17];
    __shared__ alignas(16) float sL2[16*17];

    // B-operand fragments: Q rows (col = l15, k = h slice by quad)
    bf8 qbN = *(const bf8*)(Qb + (size_t)(n0 + l15)*32 + quad*8);
    bf8 qbM = *(const bf8*)(Qb + (size_t)(m0 + l15)*32 + quad*8);
    // per-lane 4-t slices (hoisted; lane owns t = quad*4..quad*4+3)
    float4 qb4 = *(const float4*)(QB  + (size_t)(n0 + l15)*TP + quad*4);
    float4 qa4 = *(const float4*)(QAd + (size_t)(m0 + l15)*TP + quad*4);

    #pragma unroll
    for (int j = 0; j < 4; j++) {
        int m = m0 + wv*4 + j;
        // G' = A1[m](rows t, k=h) x Q(k=h, cols n) -> D[t][n]; lane: t=quad*4+r, n=l15
        bf8 aA1 = *(const bf8*)(A1 + (size_t)m*512 + l15*32 + quad*8);
        f4 z = {0.f,0.f,0.f,0.f};
        f4 g = __builtin_amdgcn_mfma_f32_16x16x32_bf16(aA1, qbN, z, 0, 0, 0);
        // coalesced 8B loads: 4 consecutive t for (n=l15, tq=quad)
        uint2 ax = *(const uint2*)(adjPT + (size_t)m*8192 + (n0 + l15)*16 + quad*4); // adjD[n,m,t]
        uint2 ay = *(const uint2*)(adjP  + (size_t)m*8192 + (n0 + l15)*16 + quad*4); // adjD[m,n,t]
        float v;
        v = bf2f((u16)(ax.x & 0xffffu)) * g[0];
        v = fmaf(bf2f((u16)(ax.x >> 16)),     g[1], v);
        v = fmaf(bf2f((u16)(ax.y & 0xffffu)), g[2], v);
        v = fmaf(bf2f((u16)(ax.y >> 16)),     g[3], v);
        v = fmaf(bf2f((u16)(ay.x & 0xffffu)), qb4.x, v);
        v = fmaf(bf2f((u16)(ay.x >> 16)),     qb4.y, v);
        v = fmaf(bf2f((u16)(ay.y & 0xffffu)), qb4.z, v);
        v = fmaf(bf2f((u16)(ay.y >> 16)),     qb4.w, v);
        v += __shfl_xor(v, 16, 64);
        v += __shfl_xor(v, 32, 64);
        if (quad == 0) sL1[l15*17 + wv*4 + j] = v;
    }
    #pragma unroll
    for (int j = 0; j < 4; j++) {
        int n = n0 + wv*4 + j;
        // H' = B1[n](rows t, k=h) x Q(k=h, cols m) -> D[t][m]; lane: t=quad*4+r, m=l15
        bf8 aB1 = *(const bf8*)(B1 + (size_t)n*512 + l15*32 + quad*8);
        f4 z = {0.f,0.f,0.f,0.f};
        f4 h = __builtin_amdgcn_mfma_f32_16x16x32_bf16(aB1, qbM, z, 0, 0, 0);
        uint2 ax = *(const uint2*)(adjPT + (size_t)n*8192 + (m0 + l15)*16 + quad*4); // adjD[m,n,t]
        uint2 ay = *(const uint2*)(adjP  + (size_t)n*8192 + (m0 + l15)*16 + quad*4); // adjD[n,m,t]
        float v;
        v = bf2f((u16)(ax.x & 0xffffu)) * h[0];
        v = fmaf(bf2f((u16)(ax.x >> 16)),     h[1], v);
        v = fmaf(bf2f((u16)(ax.y & 0xffffu)), h[2], v);
        v = fmaf(bf2f((u16)(ax.y >> 16)),     h[3], v);
        v = fmaf(bf2f((u16)(ay.x & 0xffffu)), qa4.x, v);
        v = fmaf(bf2f((u16)(ay.x >> 16)),     qa4.y, v);
        v = fmaf(bf2f((u16)(ay.y & 0xffffu)), qa4.z, v);
        v = fmaf(bf2f((u16)(ay.y >> 16)),     qa4.w, v);
        v += __shfl_xor(v, 16, 64);
        v += __shfl_xor(v, 32, 64);
        if (quad == 0) sL2[l15*17 + wv*4 + j] = v;
    }
    __syncthreads();
    int row = tid >> 4, col = tid & 15;
    L1 [(size_t)(n0+row)*NNODE + m0 + col] = sL1[row*17+col];
    L2T[(size_t)(m0+row)*NNODE + n0 + col] = sL2[row*17+col];
}

// ---------------------------------------------------------------------------
// K3: softmax over a 512-row + FUSED W-build and u/v reduction.
// u[16] reduce is exchange-and-halve: 17 shuffles (was 96).
// ---------------------------------------------------------------------------
__global__ __launch_bounds__(256) void k_softmax_w(
    const float* __restrict__ L1, const float* __restrict__ L2T,
    const u16* __restrict__ adjP, const u16* __restrict__ adjPT,
    u16* __restrict__ W1c, u16* __restrict__ W2c,
    float* __restrict__ u1, float* __restrict__ v2)
{
    int b = blockIdx.x, tid = threadIdx.x;
    bool first = b < NNODE;
    int j = first ? b : b - NNODE;
    const float* row = first ? (L1 + (size_t)j*NNODE) : (L2T + (size_t)j*NNODE);
    u16* W  = (first ? W1c : W2c) + (size_t)j*8192;
    float* uv = (first ? u1 : v2) + (size_t)j*TP;

    float v0 = row[tid], v1 = row[tid+256];
    float mx = fmaxf(v0, v1);
    #pragma unroll
    for (int o=32; o; o>>=1) mx = fmaxf(mx, __shfl_xor(mx, o, 64));
    __shared__ alignas(16) float red[4], red2[4], ur[4][16];
    int lane = tid & 63, wv = tid >> 6;
    if (!lane) red[wv] = mx;
    __syncthreads();
    mx = fmaxf(fmaxf(red[0],red[1]), fmaxf(red[2],red[3]));
    float e0 = __expf(v0 - mx), e1 = __expf(v1 - mx);
    float sm = e0 + e1;
    #pragma unroll
    for (int o=32; o; o>>=1) sm += __shfl_xor(sm, o, 64);
    if (!lane) red2[wv] = sm;
    __syncthreads();
    float inv = 1.0f / (red2[0]+red2[1]+red2[2]+red2[3]);
    float sa = e0*inv, sb = e1*inv;

    const u16* ap = adjP  + (size_t)j*8192;
    const u16* tp = adjPT + (size_t)j*8192;
    float u[16];
    #pragma unroll
    for (int t=0;t<16;t++) u[t]=0.f;
    #pragma unroll
    for (int half = 0; half < 2; half++) {
        int k = tid + half*256;
        float sv = half ? sb : sa;
        const uint4* p = (const uint4*)(ap + k*16);
        float av[16]; unpack8(p[0], av); unpack8(p[1], av+8);
        u16 o16[16];
        #pragma unroll
        for (int t=0;t<16;t++) o16[t] = f2bf(sv*av[t]);
        uint4* wp = (uint4*)(W + k*16);
        wp[0] = pack8(o16); wp[1] = pack8(o16+8);
        const uint4* q = (const uint4*)(tp + k*16);
        float tv[16]; unpack8(q[0], tv); unpack8(q[1], tv+8);
        #pragma unroll
        for (int t=0;t<16;t++) u[t] = fmaf(sv, tv[t], u[t]);
    }
    // exchange-and-halve: after step for xor-bit b, lane keeps half its slots.
    #pragma unroll
    for (int i=0;i<8;i++) {
        float s0 = (lane&1) ? u[i] : u[i+8];
        float r0 = __shfl_xor(s0, 1, 64);
        u[i] = ((lane&1) ? u[i+8] : u[i]) + r0;
    }
    #pragma unroll
    for (int i=0;i<4;i++) {
        float s0 = (lane&2) ? u[i] : u[i+4];
        float r0 = __shfl_xor(s0, 2, 64);
        u[i] = ((lane&2) ? u[i+4] : u[i]) + r0;
    }
    #pragma unroll
    for (int i=0;i<2;i++) {
        float s0 = (lane&4) ? u[i] : u[i+2];
        float r0 = __shfl_xor(s0, 4, 64);
        u[i] = ((lane&4) ? u[i+2] : u[i]) + r0;
    }
    {
        float s0 = (lane&8) ? u[0] : u[1];
        float r0 = __shfl_xor(s0, 8, 64);
        u[0] = ((lane&8) ? u[1] : u[0]) + r0;
    }
    u[0] += __shfl_xor(u[0], 16, 64);
    u[0] += __shfl_xor(u[0], 32, 64);
    if (lane < 16) {
        int tm = ((lane&1)<<3) | ((lane&2)<<1) | ((lane&4)>>1) | ((lane&8)>>3);
        ur[wv][tm] = u[0];
    }
    __syncthreads();
    if (tid < 16) uv[tid] = ur[0][tid]+ur[1][tid]+ur[2][tid]+ur[3][tid];
}

// ---------------------------------------------------------------------------
// K4: MFMA GEMM temp[j,d] = W1c[j,:]·A2T[d,:] + W2c[j,:]·B2T[d,:]
// (M=512, N=32, K=8192 split into 16 k-chunks; partials to tempP)
// ---------------------------------------------------------------------------
__global__ __launch_bounds__(256) void k_gemm2(
    const u16* __restrict__ W1c, const u16* __restrict__ W2c,
    const u16* __restrict__ A2T, const u16* __restrict__ B2T,
    float* __restrict__ tempP)
{
    int tid = threadIdx.x;
    int wv = tid >> 6, lane = tid & 63, l15 = lane & 15, quad = lane >> 4;
    int w = blockIdx.x*4 + wv;             // 0..1023
    int kc = w & 15, dt = (w >> 4) & 1, jt = w >> 5;
    size_t aRow = (size_t)(jt*16 + l15)*8192;
    size_t bRow = (size_t)(dt*16 + l15)*8192;
    int kt0 = kc*512 + quad*8;
    f4 acc = {0.f, 0.f, 0.f, 0.f};
    #pragma unroll
    for (int s = 0; s < 16; s++) {
        int kt = kt0 + s*32;
        bf8 aw1 = *(const bf8*)(W1c + aRow + kt);
        bf8 ba2 = *(const bf8*)(A2T + bRow + kt);
        acc = __builtin_amdgcn_mfma_f32_16x16x32_bf16(aw1, ba2, acc, 0, 0, 0);
        bf8 aw2 = *(const bf8*)(W2c + aRow + kt);
        bf8 bb2 = *(const bf8*)(B2T + bRow + kt);
        acc = __builtin_amdgcn_mfma_f32_16x16x32_bf16(aw2, bb2, acc, 0, 0, 0);
    }
    #pragma unroll
    for (int r = 0; r < 4; r++)
        tempP[((size_t)kc*NNODE + jt*16 + quad*4 + r)*DD + dt*16 + l15] = acc[r];
}

// ---------------------------------------------------------------------------
// K5: reduce k-chunk partials, add self terms (u1·B2T + v2·A2T), lrelu, out.
// ---------------------------------------------------------------------------
__global__ __launch_bounds__(256) void k_final(
    const float* __restrict__ tempP, const float* __restrict__ u1, const float* __restrict__ v2,
    const u16* __restrict__ A2T, const u16* __restrict__ B2T, float* __restrict__ out)
{
    int base = blockIdx.x * 256 + threadIdx.x;   // 0..16383 over 64 blocks
    int j = base >> 5, d = base & 31;
    float acc = 0.f;
    #pragma unroll
    for (int kc=0;kc<16;kc++) acc += tempP[((size_t)kc*NNODE + j)*DD + d];
    const uint4* pb2 = (const uint4*)(B2T + (size_t)d*8192 + j*16);
    const uint4* pa2 = (const uint4*)(A2T + (size_t)d*8192 + j*16);
    float bv[16], av[16];
    unpack8(pb2[0], bv); unpack8(pb2[1], bv+8);
    unpack8(pa2[0], av); unpack8(pa2[1], av+8);
    #pragma unroll
    for (int t = 0; t < 16; t++)
        acc += u1[(size_t)j*TP + t]*bv[t] + v2[(size_t)j*TP + t]*av[t];
    out[(size_t)j*DD + d] = fmaxf(acc, 0.2f*acc);
}

// ---------------------------------------------------------------------------
extern "C" void kernel_launch(void* const* d_in, const int* in_sizes, int n_in,
                              void* d_out, int out_size, void* d_ws, size_t ws_size,
                              hipStream_t stream)
{
    (void)in_sizes; (void)n_in; (void)out_size; (void)ws_size;
    const float* x   = (const float*)d_in[0];
    const float* adj = (const float*)d_in[1];
    const float* W1  = (const float*)d_in[2];
    const float* W2  = (const float*)d_in[3];
    const float* W3  = (const float*)d_in[4];

    char* ws = (char*)d_ws;
    u16*   adjP = (u16*)(ws);                   // 8 MB
    u16*   adjPT= (u16*)(ws + 0x800000);        // 8 MB
    u16*   W1c  = (u16*)(ws + 0x1000000);       // 8 MB
    u16*   W2c  = (u16*)(ws + 0x1800000);       // 8 MB
    u16*   A1   = (u16*)(ws + 0x2000000);       // 512 KB each
    u16*   B1   = (u16*)(ws + 0x2080000);
    u16*   A2T  = (u16*)(ws + 0x2100000);
    u16*   B2T  = (u16*)(ws + 0x2180000);
    u16*   Qb   = (u16*)(ws + 0x2200000);       // 32 KB
    float* QAd  = (float*)(ws + 0x2210000);
    float* QB   = (float*)(ws + 0x2220000);
    float* u1   = (float*)(ws + 0x2230000);
    float* v2   = (float*)(ws + 0x2240000);
    float* L1   = (float*)(ws + 0x2300000);     // 1 MB
    float* L2T  = (float*)(ws + 0x2400000);     // 1 MB
    float* tempP= (float*)(ws + 0x2500000);     // 1 MB

    k_prep_adjp<<<768, 256, 0, stream>>>(x, W1, W2, W3, adj,
                                         A1, B1, A2T, B2T, Qb, QAd, QB, adjP, adjPT);
    k_logits<<<dim3(32,32), 256, 0, stream>>>(Qb, A1, B1, adjP, adjPT, QAd, QB, L1, L2T);
    k_softmax_w<<<1024, 256, 0, stream>>>(L1, L2T, adjP, adjPT, W1c, W2c, u1, v2);
    k_gemm2<<<256, 256, 0, stream>>>(W1c, W2c, A2T, B2T, tempP);
    k_final<<<64, 256, 0, stream>>>(tempP, u1, v2, A2T, B2T, (float*)d_out);
}

// Round 2
// 103.440 us; speedup vs baseline: 1.1239x; 1.0324x over previous
//
#include <hip/hip_runtime.h>
#include <hip/hip_bf16.h>

#define NNODE 512
#define CCH   16
#define TT    15
#define TP    16
#define HH    32
#define DD    32

typedef unsigned short u16;
typedef unsigned int   u32;
typedef short bf8 __attribute__((ext_vector_type(8)));   // 8 bf16 = 4 VGPR (MFMA A/B frag)
typedef float f4  __attribute__((ext_vector_type(4)));   // MFMA C/D frag

__device__ __forceinline__ float bf2f(u16 v) {
    union { u32 u; float f; } x; x.u = ((u32)v) << 16; return x.f;
}
__device__ __forceinline__ u16 f2bf(float f) {
    union { float f; u32 u; } x; x.f = f;
    u32 u = x.u;
    return (u16)((u + 0x7FFFu + ((u >> 16) & 1u)) >> 16);
}
__device__ __forceinline__ void unpack8(uint4 p, float* o) {
    o[0]=bf2f((u16)(p.x & 0xffffu)); o[1]=bf2f((u16)(p.x >> 16));
    o[2]=bf2f((u16)(p.y & 0xffffu)); o[3]=bf2f((u16)(p.y >> 16));
    o[4]=bf2f((u16)(p.z & 0xffffu)); o[5]=bf2f((u16)(p.z >> 16));
    o[6]=bf2f((u16)(p.w & 0xffffu)); o[7]=bf2f((u16)(p.w >> 16));
}
__device__ __forceinline__ uint4 pack8(const u16* v) {
    return make_uint4((u32)v[0]|((u32)v[1]<<16), (u32)v[2]|((u32)v[3]<<16),
                      (u32)v[4]|((u32)v[5]<<16), (u32)v[6]|((u32)v[7]<<16));
}

// ---------------------------------------------------------------------------
// K1: blocks 0..511: per-node prep: A1/B1 bf16 [n][t*32+h], Qb bf16,
//     QAd/QB f32, A2T/B2T [d][(k=n)*16+t] via coalesced u32 stores.
//     blocks 512..767: 32x32 adjacency tiles -> adjP[n][m*16+t] AND
//     adjPT[m][n*16+t] (bf16, diag folded into t=15).
// ---------------------------------------------------------------------------
__global__ __launch_bounds__(256) void k_prep_adjp(
    const float* __restrict__ x, const float* __restrict__ W1,
    const float* __restrict__ W2, const float* __restrict__ W3,
    const float* __restrict__ adj,
    u16* __restrict__ A1, u16* __restrict__ B1,
    u16* __restrict__ A2T, u16* __restrict__ B2T,
    u16* __restrict__ Qb, float* __restrict__ QAd, float* __restrict__ QB,
    u16* __restrict__ adjP, u16* __restrict__ adjPT)
{
    int tid = threadIdx.x;
    if (blockIdx.x < 512) {
        int n = blockIdx.x;
        __shared__ alignas(16) float xs[CCH];
        __shared__ alignas(16) float A1row[512], B1row[512];
        __shared__ alignas(16) float A2row[512], B2row[512];
        __shared__ alignas(16) float Qs[HH];
        if (tid < CCH) xs[tid] = x[n*CCH + tid];
        __syncthreads();
        float xr[CCH];
        #pragma unroll
        for (int i=0;i<CCH;i++) xr[i]=xs[i];
        #pragma unroll
        for (int rep=0; rep<2; rep++) {
            int c = tid + rep*256;
            float a1=0.f,b1=0.f,a2=0.f,b2=0.f;
            #pragma unroll
            for (int i=0;i<CCH;i++) {
                a1 += xr[i]*W1[i*512 + c];
                b1 += xr[i]*W1[(CCH+i)*512 + c];
                a2 += xr[i]*W2[i*512 + c];
                b2 += xr[i]*W2[(CCH+i)*512 + c];
            }
            A1[(size_t)n*512 + c]=f2bf(a1); B1[(size_t)n*512 + c]=f2bf(b1);
            A1row[c]=a1; B1row[c]=b1; A2row[c]=a2; B2row[c]=b2;
        }
        if (tid < HH) {
            float q=0.f;
            #pragma unroll
            for (int i=0;i<CCH;i++) q += xr[i]*W3[i*HH + tid];
            Qs[tid]=q; Qb[(size_t)n*HH + tid]=f2bf(q);
        }
        __syncthreads();
        if (tid < TP) {
            float qa=0.f, qb=0.f;
            #pragma unroll
            for (int h=0;h<HH;h++) { qa += Qs[h]*A1row[tid*HH+h]; qb += Qs[h]*B1row[tid*HH+h]; }
            QAd[(size_t)n*TP + tid]=qa; QB[(size_t)n*TP + tid]=qb;
        }
        {   // A2T/B2T: [d][n*16+t]; coalesced u32 stores
            int d = tid >> 3, t0 = (tid & 7) * 2;
            u32 pa = (u32)f2bf(A2row[t0*32 + d]) | ((u32)f2bf(A2row[(t0+1)*32 + d]) << 16);
            u32 pb = (u32)f2bf(B2row[t0*32 + d]) | ((u32)f2bf(B2row[(t0+1)*32 + d]) << 16);
            *(u32*)(A2T + (size_t)d*8192 + n*16 + t0) = pa;
            *(u32*)(B2T + (size_t)d*8192 + n*16 + t0) = pb;
        }
    } else {
        int b = blockIdx.x - 512;            // 0..255
        int n0 = (b >> 4) * 32, m0 = (b & 15) * 32;
        __shared__ alignas(16) u16 s[32*520];  // stride 520 (1040B=65*16)
        #pragma unroll
        for (int i = 0; i < 60; i++) {
            int e = tid + i*256;
            int nl = e / 480; int rem = e - nl*480;
            int ml = rem / 15; int t = rem - ml*15;
            float v = adj[((size_t)(n0+nl)*512 + (m0+ml))*TT + t];
            s[nl*520 + ml*16 + t] = f2bf(v);
        }
        #pragma unroll
        for (int i = 0; i < 4; i++) {
            int e = tid + i*256; int nl = e >> 5, ml = e & 31;
            s[nl*520 + ml*16 + 15] = ((n0+nl) == (m0+ml)) ? (u16)0x3F80 : (u16)0;
        }
        __syncthreads();
        #pragma unroll
        for (int i = 0; i < 8; i++) {        // adjP: 32 rows x 1KB
            int c = tid + i*256;
            int nl = c >> 6, off = (c & 63) * 8;
            uint4 vv = *(const uint4*)(s + nl*520 + off);
            *(uint4*)(adjP + (size_t)(n0+nl)*8192 + m0*16 + off) = vv;
        }
        #pragma unroll
        for (int i = 0; i < 8; i++) {        // adjPT: 32 rows x 1KB (transposed)
            int c = tid + i*256;
            int ml = c >> 6, nlh = c & 63, nl = nlh >> 1, half = nlh & 1;
            uint4 vv = *(const uint4*)(s + nl*520 + ml*16 + half*8);
            *(uint4*)(adjPT + (size_t)(m0+ml)*8192 + (n0+nl)*16 + half*8) = vv;
        }
    }
}

// ---------------------------------------------------------------------------
// K2: fused logits (swapped-operand MFMA; 2 shuffles per output).
// ---------------------------------------------------------------------------
__global__ __launch_bounds__(256) void k_logits(
    const u16* __restrict__ Qb, const u16* __restrict__ A1, const u16* __restrict__ B1,
    const u16* __restrict__ adjP, const u16* __restrict__ adjPT,
    const float* __restrict__ QAd, const float* __restrict__ QB,
    float* __restrict__ L1, float* __restrict__ L2T)
{
    const int m0 = blockIdx.x * 16, n0 = blockIdx.y * 16;
    const int tid = threadIdx.x;
    const int wv = tid >> 6, lane = tid & 63, l15 = lane & 15, quad = lane >> 4;
    __shared__ alignas(16) float sL1[16*17];
    __shared__ alignas(16) float sL2[16*17];

    bf8 qbN = *(const bf8*)(Qb + (size_t)(n0 + l15)*32 + quad*8);
    bf8 qbM = *(const bf8*)(Qb + (size_t)(m0 + l15)*32 + quad*8);
    float4 qb4 = *(const float4*)(QB  + (size_t)(n0 + l15)*TP + quad*4);
    float4 qa4 = *(const float4*)(QAd + (size_t)(m0 + l15)*TP + quad*4);

    #pragma unroll
    for (int j = 0; j < 4; j++) {
        int m = m0 + wv*4 + j;
        bf8 aA1 = *(const bf8*)(A1 + (size_t)m*512 + l15*32 + quad*8);
        f4 z = {0.f,0.f,0.f,0.f};
        f4 g = __builtin_amdgcn_mfma_f32_16x16x32_bf16(aA1, qbN, z, 0, 0, 0);
        uint2 ax = *(const uint2*)(adjPT + (size_t)m*8192 + (n0 + l15)*16 + quad*4);
        uint2 ay = *(const uint2*)(adjP  + (size_t)m*8192 + (n0 + l15)*16 + quad*4);
        float v;
        v = bf2f((u16)(ax.x & 0xffffu)) * g[0];
        v = fmaf(bf2f((u16)(ax.x >> 16)),     g[1], v);
        v = fmaf(bf2f((u16)(ax.y & 0xffffu)), g[2], v);
        v = fmaf(bf2f((u16)(ax.y >> 16)),     g[3], v);
        v = fmaf(bf2f((u16)(ay.x & 0xffffu)), qb4.x, v);
        v = fmaf(bf2f((u16)(ay.x >> 16)),     qb4.y, v);
        v = fmaf(bf2f((u16)(ay.y & 0xffffu)), qb4.z, v);
        v = fmaf(bf2f((u16)(ay.y >> 16)),     qb4.w, v);
        v += __shfl_xor(v, 16, 64);
        v += __shfl_xor(v, 32, 64);
        if (quad == 0) sL1[l15*17 + wv*4 + j] = v;
    }
    #pragma unroll
    for (int j = 0; j < 4; j++) {
        int n = n0 + wv*4 + j;
        bf8 aB1 = *(const bf8*)(B1 + (size_t)n*512 + l15*32 + quad*8);
        f4 z = {0.f,0.f,0.f,0.f};
        f4 h = __builtin_amdgcn_mfma_f32_16x16x32_bf16(aB1, qbM, z, 0, 0, 0);
        uint2 ax = *(const uint2*)(adjPT + (size_t)n*8192 + (m0 + l15)*16 + quad*4);
        uint2 ay = *(const uint2*)(adjP  + (size_t)n*8192 + (m0 + l15)*16 + quad*4);
        float v;
        v = bf2f((u16)(ax.x & 0xffffu)) * h[0];
        v = fmaf(bf2f((u16)(ax.x >> 16)),     h[1], v);
        v = fmaf(bf2f((u16)(ax.y & 0xffffu)), h[2], v);
        v = fmaf(bf2f((u16)(ax.y >> 16)),     h[3], v);
        v = fmaf(bf2f((u16)(ay.x & 0xffffu)), qa4.x, v);
        v = fmaf(bf2f((u16)(ay.x >> 16)),     qa4.y, v);
        v = fmaf(bf2f((u16)(ay.y & 0xffffu)), qa4.z, v);
        v = fmaf(bf2f((u16)(ay.y >> 16)),     qa4.w, v);
        v += __shfl_xor(v, 16, 64);
        v += __shfl_xor(v, 32, 64);
        if (quad == 0) sL2[l15*17 + wv*4 + j] = v;
    }
    __syncthreads();
    int row = tid >> 4, col = tid & 15;
    L1 [(size_t)(n0+row)*NNODE + m0 + col] = sL1[row*17+col];
    L2T[(size_t)(m0+row)*NNODE + n0 + col] = sL2[row*17+col];
}

// ---------------------------------------------------------------------------
// K34: FUSED softmax + W-chunk build (LDS, XOR-swizzled) + MFMA GEMM + u-part.
// grid (32 j-tiles, 16 kc chunks, 2 dir). Eliminates the W1c/W2c 48MB
// round-trip and one kernel launch.
//   dir 0: s = softmax(L1 row j);  W = s*adjP[j]  vs A2T;  u-part from adjPT
//   dir 1: s = softmax(L2T row j); W = s*adjP[j]  vs B2T;  u-part from adjPT
// Partials: tempP2[(dir*16+kc)][j][d], uP[(dir*16+kc)][j][t]; K5 reduces.
// ---------------------------------------------------------------------------
__global__ __launch_bounds__(256) void k_smx_gemm(
    const float* __restrict__ L1, const float* __restrict__ L2T,
    const u16* __restrict__ adjP, const u16* __restrict__ adjPT,
    const u16* __restrict__ A2T, const u16* __restrict__ B2T,
    float* __restrict__ tempP2, float* __restrict__ uP)
{
    const int j0 = blockIdx.x * 16, kc = blockIdx.y, dir = blockIdx.z;
    const int tid = threadIdx.x;
    const int wv = tid >> 6, lane = tid & 63, l15 = lane & 15, quad = lane >> 4;
    const float* Lbase = dir ? L2T : L1;

    __shared__ alignas(16) u16 Wt[16*512];      // 16KB: W chunk, 16B-slot XOR swizzle
    __shared__ alignas(16) float redb[4][512];  // 8KB: cross-wave MFMA reduce
    __shared__ float mxs[16], invs[16];

    // ---- phase 0: softmax stats (wave w handles rows 4w..4w+3) ----
    #pragma unroll
    for (int rr = 0; rr < 4; rr++) {
        int jr = wv*4 + rr;
        const float* rw = Lbase + (size_t)(j0 + jr)*NNODE;
        float4 a = *(const float4*)(rw + lane*8);
        float4 b = *(const float4*)(rw + lane*8 + 4);
        float mx = fmaxf(fmaxf(fmaxf(a.x,a.y),fmaxf(a.z,a.w)),
                         fmaxf(fmaxf(b.x,b.y),fmaxf(b.z,b.w)));
        #pragma unroll
        for (int o=32; o; o>>=1) mx = fmaxf(mx, __shfl_xor(mx, o, 64));
        float sm = __expf(a.x-mx)+__expf(a.y-mx)+__expf(a.z-mx)+__expf(a.w-mx)
                 + __expf(b.x-mx)+__expf(b.y-mx)+__expf(b.z-mx)+__expf(b.w-mx);
        #pragma unroll
        for (int o=32; o; o>>=1) sm += __shfl_xor(sm, o, 64);
        if (lane == 0) { mxs[jr] = mx; invs[jr] = 1.0f/sm; }
    }
    __syncthreads();

    // ---- phase 1: W-chunk build + u partial ----
    {
        int j = tid >> 4, cb = tid & 15;      // j row 0..15, cb = 32-elem column blk
        float mxj = mxs[j], invj = invs[j];
        int mg = kc*32 + cb*2;
        const float* rw = Lbase + (size_t)(j0 + j)*NNODE;
        float s0 = __expf(rw[mg]   - mxj) * invj;
        float s1 = __expf(rw[mg+1] - mxj) * invj;

        const uint4* pp = (const uint4*)(adjP + (size_t)(j0+j)*8192 + kc*512 + cb*32);
        float av[32];
        unpack8(pp[0], av); unpack8(pp[1], av+8); unpack8(pp[2], av+16); unpack8(pp[3], av+24);
        u16 wo[32];
        #pragma unroll
        for (int e=0;e<16;e++) wo[e]    = f2bf(s0*av[e]);
        #pragma unroll
        for (int e=0;e<16;e++) wo[16+e] = f2bf(s1*av[16+e]);
        #pragma unroll
        for (int q=0;q<4;q++) {
            int sl = (cb*4 + q) ^ (j & 7);    // swizzled 16B slot
            *(uint4*)&Wt[j*512 + sl*8] = pack8(wo + q*8);
        }

        const uint4* qq4 = (const uint4*)(adjPT + (size_t)(j0+j)*8192 + kc*512 + cb*32);
        float tv[32];
        unpack8(qq4[0], tv); unpack8(qq4[1], tv+8); unpack8(qq4[2], tv+16); unpack8(qq4[3], tv+24);
        float ut[16];
        #pragma unroll
        for (int t=0;t<16;t++) ut[t] = s0*tv[t] + s1*tv[16+t];
        // exchange-and-halve fold over the 16 cb-lanes (xor 1,2,4,8)
        #pragma unroll
        for (int i=0;i<8;i++) {
            float v0 = (lane&1) ? ut[i] : ut[i+8];
            float r0 = __shfl_xor(v0, 1, 64);
            ut[i] = ((lane&1) ? ut[i+8] : ut[i]) + r0;
        }
        #pragma unroll
        for (int i=0;i<4;i++) {
            float v0 = (lane&2) ? ut[i] : ut[i+4];
            float r0 = __shfl_xor(v0, 2, 64);
            ut[i] = ((lane&2) ? ut[i+4] : ut[i]) + r0;
        }
        #pragma unroll
        for (int i=0;i<2;i++) {
            float v0 = (lane&4) ? ut[i] : ut[i+2];
            float r0 = __shfl_xor(v0, 4, 64);
            ut[i] = ((lane&4) ? ut[i+2] : ut[i]) + r0;
        }
        {
            float v0 = (lane&8) ? ut[0] : ut[1];
            float r0 = __shfl_xor(v0, 8, 64);
            ut[0] = ((lane&8) ? ut[1] : ut[0]) + r0;
        }
        int tm = ((cb&1)<<3) | ((cb&2)<<1) | ((cb&4)>>1) | ((cb&8)>>3);
        uP[((size_t)(dir*16 + kc)*NNODE + j0 + j)*TP + tm] = ut[0];
    }
    __syncthreads();

    // ---- phase 2: MFMA [16 j][512 k] x [512 k][32 d]; wave = k-quarter ----
    {
        const u16* Bmat = dir ? B2T : A2T;
        f4 acc0 = {0.f,0.f,0.f,0.f}, acc1 = {0.f,0.f,0.f,0.f};
        #pragma unroll
        for (int st = 0; st < 4; st++) {
            int s = wv*4 + st;
            bf8 afr = *(const bf8*)&Wt[l15*512 + (((s*4 + quad) ^ (l15 & 7)) << 3)];
            bf8 b0 = *(const bf8*)(Bmat + (size_t)(l15)*8192    + kc*512 + s*32 + quad*8);
            bf8 b1 = *(const bf8*)(Bmat + (size_t)(16+l15)*8192 + kc*512 + s*32 + quad*8);
            acc0 = __builtin_amdgcn_mfma_f32_16x16x32_bf16(afr, b0, acc0, 0, 0, 0);
            acc1 = __builtin_amdgcn_mfma_f32_16x16x32_bf16(afr, b1, acc1, 0, 0, 0);
        }
        #pragma unroll
        for (int r = 0; r < 4; r++) {
            redb[wv][      (quad*4+r)*16 + l15] = acc0[r];
            redb[wv][256 + (quad*4+r)*16 + l15] = acc1[r];
        }
    }
    __syncthreads();
    #pragma unroll
    for (int h = 0; h < 2; h++) {
        int o = tid + h*256;                 // 0..511 over (j,d)
        int jj = o >> 5, d = o & 31;
        int idx = (d >> 4)*256 + jj*16 + (d & 15);
        float v = redb[0][idx] + redb[1][idx] + redb[2][idx] + redb[3][idx];
        tempP2[(((size_t)dir*16 + kc)*NNODE + j0 + jj)*DD + d] = v;
    }
}

// ---------------------------------------------------------------------------
// K5: reduce 32 (dir,kc) partials + uP partials, add self terms, lrelu, out.
// ---------------------------------------------------------------------------
__global__ __launch_bounds__(256) void k_final(
    const float* __restrict__ tempP2, const float* __restrict__ uP,
    const u16* __restrict__ A2T, const u16* __restrict__ B2T, float* __restrict__ out)
{
    int blk = blockIdx.x, tid = threadIdx.x;
    int jbase = blk*8;                       // 8 j-rows per block
    __shared__ float u1L[8][16], v2L[8][16];
    {
        int dsel = tid >> 7;                 // 0: u1, 1: v2
        int i = tid & 127; int jj = i >> 4, t = i & 15;
        float s = 0.f;
        #pragma unroll
        for (int kcc = 0; kcc < 16; kcc++)
            s += uP[(((size_t)dsel*16 + kcc)*NNODE + jbase + jj)*TP + t];
        if (dsel) v2L[jj][t] = s; else u1L[jj][t] = s;
    }
    __syncthreads();
    int base = blk*256 + tid;                // (j,d)
    int j = base >> 5, d = base & 31, jj = j & 7;
    float acc = 0.f;
    #pragma unroll
    for (int p = 0; p < 32; p++) acc += tempP2[((size_t)p*NNODE + j)*DD + d];
    const uint4* pb2 = (const uint4*)(B2T + (size_t)d*8192 + j*16);
    const uint4* pa2 = (const uint4*)(A2T + (size_t)d*8192 + j*16);
    float bv[16], avv[16];
    unpack8(pb2[0], bv);  unpack8(pb2[1], bv+8);
    unpack8(pa2[0], avv); unpack8(pa2[1], avv+8);
    #pragma unroll
    for (int t = 0; t < 16; t++)
        acc += u1L[jj][t]*bv[t] + v2L[jj][t]*avv[t];
    out[(size_t)j*DD + d] = fmaxf(acc, 0.2f*acc);
}

// ---------------------------------------------------------------------------
extern "C" void kernel_launch(void* const* d_in, const int* in_sizes, int n_in,
                              void* d_out, int out_size, void* d_ws, size_t ws_size,
                              hipStream_t stream)
{
    (void)in_sizes; (void)n_in; (void)out_size; (void)ws_size;
    const float* x   = (const float*)d_in[0];
    const float* adj = (const float*)d_in[1];
    const float* W1  = (const float*)d_in[2];
    const float* W2  = (const float*)d_in[3];
    const float* W3  = (const float*)d_in[4];

    char* ws = (char*)d_ws;
    u16*   adjP  = (u16*)(ws);                   // 8 MB
    u16*   adjPT = (u16*)(ws + 0x800000);        // 8 MB
    u16*   A1    = (u16*)(ws + 0x1000000);       // 512 KB each
    u16*   B1    = (u16*)(ws + 0x1080000);
    u16*   A2T   = (u16*)(ws + 0x1100000);
    u16*   B2T   = (u16*)(ws + 0x1180000);
    u16*   Qb    = (u16*)(ws + 0x1200000);       // 32 KB
    float* QAd   = (float*)(ws + 0x1210000);
    float* QB    = (float*)(ws + 0x1220000);
    float* L1    = (float*)(ws + 0x1300000);     // 1 MB
    float* L2T   = (float*)(ws + 0x1400000);     // 1 MB
    float* tempP2= (float*)(ws + 0x1500000);     // 2 MB (32 partials x 512 x 32)
    float* uP    = (float*)(ws + 0x1700000);     // 1 MB (32 partials x 512 x 16)

    k_prep_adjp<<<768, 256, 0, stream>>>(x, W1, W2, W3, adj,
                                         A1, B1, A2T, B2T, Qb, QAd, QB, adjP, adjPT);
    k_logits<<<dim3(32,32), 256, 0, stream>>>(Qb, A1, B1, adjP, adjPT, QAd, QB, L1, L2T);
    k_smx_gemm<<<dim3(32,16,2), 256, 0, stream>>>(L1, L2T, adjP, adjPT, A2T, B2T, tempP2, uP);
    k_final<<<64, 256, 0, stream>>>(tempP2, uP, A2T, B2T, (float*)d_out);
}

// Round 3
// 103.157 us; speedup vs baseline: 1.1270x; 1.0027x over previous
//
#include <hip/hip_runtime.h>
#include <hip/hip_bf16.h>

#define NNODE 512
#define CCH   16
#define TT    15
#define TP    16
#define HH    32
#define DD    32

typedef unsigned short u16;
typedef unsigned int   u32;
typedef short bf8 __attribute__((ext_vector_type(8)));   // 8 bf16 = 4 VGPR (MFMA A/B frag)
typedef float f4  __attribute__((ext_vector_type(4)));   // MFMA C/D frag

__device__ __forceinline__ float bf2f(u16 v) {
    union { u32 u; float f; } x; x.u = ((u32)v) << 16; return x.f;
}
__device__ __forceinline__ u16 f2bf(float f) {
    union { float f; u32 u; } x; x.f = f;
    u32 u = x.u;
    return (u16)((u + 0x7FFFu + ((u >> 16) & 1u)) >> 16);
}
__device__ __forceinline__ void unpack8(uint4 p, float* o) {
    o[0]=bf2f((u16)(p.x & 0xffffu)); o[1]=bf2f((u16)(p.x >> 16));
    o[2]=bf2f((u16)(p.y & 0xffffu)); o[3]=bf2f((u16)(p.y >> 16));
    o[4]=bf2f((u16)(p.z & 0xffffu)); o[5]=bf2f((u16)(p.z >> 16));
    o[6]=bf2f((u16)(p.w & 0xffffu)); o[7]=bf2f((u16)(p.w >> 16));
}
__device__ __forceinline__ uint4 pack8(const u16* v) {
    return make_uint4((u32)v[0]|((u32)v[1]<<16), (u32)v[2]|((u32)v[3]<<16),
                      (u32)v[4]|((u32)v[5]<<16), (u32)v[6]|((u32)v[7]<<16));
}

// ---------------------------------------------------------------------------
// K1: blocks 0..511: per-node prep: A1/B1 bf16 [n][t*32+h], Qb bf16,
//     QAd/QB f32, A2T/B2T [d][(k=n)*16+t] via coalesced u32 stores.
//     blocks 512..767: 32x32 adjacency tiles -> adjP[n][m*16+t] AND
//     adjPT[m][n*16+t] (bf16, diag folded into t=15).
// ---------------------------------------------------------------------------
__global__ __launch_bounds__(256) void k_prep_adjp(
    const float* __restrict__ x, const float* __restrict__ W1,
    const float* __restrict__ W2, const float* __restrict__ W3,
    const float* __restrict__ adj,
    u16* __restrict__ A1, u16* __restrict__ B1,
    u16* __restrict__ A2T, u16* __restrict__ B2T,
    u16* __restrict__ Qb, float* __restrict__ QAd, float* __restrict__ QB,
    u16* __restrict__ adjP, u16* __restrict__ adjPT)
{
    int tid = threadIdx.x;
    if (blockIdx.x < 512) {
        int n = blockIdx.x;
        __shared__ alignas(16) float xs[CCH];
        __shared__ alignas(16) float A1row[512], B1row[512];
        __shared__ alignas(16) float A2row[512], B2row[512];
        __shared__ alignas(16) float Qs[HH];
        if (tid < CCH) xs[tid] = x[n*CCH + tid];
        __syncthreads();
        float xr[CCH];
        #pragma unroll
        for (int i=0;i<CCH;i++) xr[i]=xs[i];
        #pragma unroll
        for (int rep=0; rep<2; rep++) {
            int c = tid + rep*256;
            float a1=0.f,b1=0.f,a2=0.f,b2=0.f;
            #pragma unroll
            for (int i=0;i<CCH;i++) {
                a1 += xr[i]*W1[i*512 + c];
                b1 += xr[i]*W1[(CCH+i)*512 + c];
                a2 += xr[i]*W2[i*512 + c];
                b2 += xr[i]*W2[(CCH+i)*512 + c];
            }
            A1[(size_t)n*512 + c]=f2bf(a1); B1[(size_t)n*512 + c]=f2bf(b1);
            A1row[c]=a1; B1row[c]=b1; A2row[c]=a2; B2row[c]=b2;
        }
        if (tid < HH) {
            float q=0.f;
            #pragma unroll
            for (int i=0;i<CCH;i++) q += xr[i]*W3[i*HH + tid];
            Qs[tid]=q; Qb[(size_t)n*HH + tid]=f2bf(q);
        }
        __syncthreads();
        if (tid < TP) {
            float qa=0.f, qb=0.f;
            #pragma unroll
            for (int h=0;h<HH;h++) { qa += Qs[h]*A1row[tid*HH+h]; qb += Qs[h]*B1row[tid*HH+h]; }
            QAd[(size_t)n*TP + tid]=qa; QB[(size_t)n*TP + tid]=qb;
        }
        {   // A2T/B2T: [d][n*16+t]; coalesced u32 stores
            int d = tid >> 3, t0 = (tid & 7) * 2;
            u32 pa = (u32)f2bf(A2row[t0*32 + d]) | ((u32)f2bf(A2row[(t0+1)*32 + d]) << 16);
            u32 pb = (u32)f2bf(B2row[t0*32 + d]) | ((u32)f2bf(B2row[(t0+1)*32 + d]) << 16);
            *(u32*)(A2T + (size_t)d*8192 + n*16 + t0) = pa;
            *(u32*)(B2T + (size_t)d*8192 + n*16 + t0) = pb;
        }
    } else {
        int b = blockIdx.x - 512;            // 0..255
        int n0 = (b >> 4) * 32, m0 = (b & 15) * 32;
        __shared__ alignas(16) u16 s[32*520];  // stride 520 (1040B=65*16)
        #pragma unroll
        for (int i = 0; i < 60; i++) {
            int e = tid + i*256;
            int nl = e / 480; int rem = e - nl*480;
            int ml = rem / 15; int t = rem - ml*15;
            float v = adj[((size_t)(n0+nl)*512 + (m0+ml))*TT + t];
            s[nl*520 + ml*16 + t] = f2bf(v);
        }
        #pragma unroll
        for (int i = 0; i < 4; i++) {
            int e = tid + i*256; int nl = e >> 5, ml = e & 31;
            s[nl*520 + ml*16 + 15] = ((n0+nl) == (m0+ml)) ? (u16)0x3F80 : (u16)0;
        }
        __syncthreads();
        #pragma unroll
        for (int i = 0; i < 8; i++) {        // adjP: 32 rows x 1KB
            int c = tid + i*256;
            int nl = c >> 6, off = (c & 63) * 8;
            uint4 vv = *(const uint4*)(s + nl*520 + off);
            *(uint4*)(adjP + (size_t)(n0+nl)*8192 + m0*16 + off) = vv;
        }
        #pragma unroll
        for (int i = 0; i < 8; i++) {        // adjPT: 32 rows x 1KB (transposed)
            int c = tid + i*256;
            int ml = c >> 6, nlh = c & 63, nl = nlh >> 1, half = nlh & 1;
            uint4 vv = *(const uint4*)(s + nl*520 + ml*16 + half*8);
            *(uint4*)(adjPT + (size_t)(m0+ml)*8192 + (n0+nl)*16 + half*8) = vv;
        }
    }
}

// ---------------------------------------------------------------------------
// K2: fused logits (swapped-operand MFMA; 2 shuffles per output).
// ---------------------------------------------------------------------------
__global__ __launch_bounds__(256) void k_logits(
    const u16* __restrict__ Qb, const u16* __restrict__ A1, const u16* __restrict__ B1,
    const u16* __restrict__ adjP, const u16* __restrict__ adjPT,
    const float* __restrict__ QAd, const float* __restrict__ QB,
    float* __restrict__ L1, float* __restrict__ L2T)
{
    const int m0 = blockIdx.x * 16, n0 = blockIdx.y * 16;
    const int tid = threadIdx.x;
    const int wv = tid >> 6, lane = tid & 63, l15 = lane & 15, quad = lane >> 4;
    __shared__ alignas(16) float sL1[16*17];
    __shared__ alignas(16) float sL2[16*17];

    bf8 qbN = *(const bf8*)(Qb + (size_t)(n0 + l15)*32 + quad*8);
    bf8 qbM = *(const bf8*)(Qb + (size_t)(m0 + l15)*32 + quad*8);
    float4 qb4 = *(const float4*)(QB  + (size_t)(n0 + l15)*TP + quad*4);
    float4 qa4 = *(const float4*)(QAd + (size_t)(m0 + l15)*TP + quad*4);

    #pragma unroll
    for (int j = 0; j < 4; j++) {
        int m = m0 + wv*4 + j;
        bf8 aA1 = *(const bf8*)(A1 + (size_t)m*512 + l15*32 + quad*8);
        f4 z = {0.f,0.f,0.f,0.f};
        f4 g = __builtin_amdgcn_mfma_f32_16x16x32_bf16(aA1, qbN, z, 0, 0, 0);
        uint2 ax = *(const uint2*)(adjPT + (size_t)m*8192 + (n0 + l15)*16 + quad*4);
        uint2 ay = *(const uint2*)(adjP  + (size_t)m*8192 + (n0 + l15)*16 + quad*4);
        float v;
        v = bf2f((u16)(ax.x & 0xffffu)) * g[0];
        v = fmaf(bf2f((u16)(ax.x >> 16)),     g[1], v);
        v = fmaf(bf2f((u16)(ax.y & 0xffffu)), g[2], v);
        v = fmaf(bf2f((u16)(ax.y >> 16)),     g[3], v);
        v = fmaf(bf2f((u16)(ay.x & 0xffffu)), qb4.x, v);
        v = fmaf(bf2f((u16)(ay.x >> 16)),     qb4.y, v);
        v = fmaf(bf2f((u16)(ay.y & 0xffffu)), qb4.z, v);
        v = fmaf(bf2f((u16)(ay.y >> 16)),     qb4.w, v);
        v += __shfl_xor(v, 16, 64);
        v += __shfl_xor(v, 32, 64);
        if (quad == 0) sL1[l15*17 + wv*4 + j] = v;
    }
    #pragma unroll
    for (int j = 0; j < 4; j++) {
        int n = n0 + wv*4 + j;
        bf8 aB1 = *(const bf8*)(B1 + (size_t)n*512 + l15*32 + quad*8);
        f4 z = {0.f,0.f,0.f,0.f};
        f4 h = __builtin_amdgcn_mfma_f32_16x16x32_bf16(aB1, qbM, z, 0, 0, 0);
        uint2 ax = *(const uint2*)(adjPT + (size_t)n*8192 + (m0 + l15)*16 + quad*4);
        uint2 ay = *(const uint2*)(adjP  + (size_t)n*8192 + (m0 + l15)*16 + quad*4);
        float v;
        v = bf2f((u16)(ax.x & 0xffffu)) * h[0];
        v = fmaf(bf2f((u16)(ax.x >> 16)),     h[1], v);
        v = fmaf(bf2f((u16)(ax.y & 0xffffu)), h[2], v);
        v = fmaf(bf2f((u16)(ax.y >> 16)),     h[3], v);
        v = fmaf(bf2f((u16)(ay.x & 0xffffu)), qa4.x, v);
        v = fmaf(bf2f((u16)(ay.x >> 16)),     qa4.y, v);
        v = fmaf(bf2f((u16)(ay.y & 0xffffu)), qa4.z, v);
        v = fmaf(bf2f((u16)(ay.y >> 16)),     qa4.w, v);
        v += __shfl_xor(v, 16, 64);
        v += __shfl_xor(v, 32, 64);
        if (quad == 0) sL2[l15*17 + wv*4 + j] = v;
    }
    __syncthreads();
    int row = tid >> 4, col = tid & 15;
    L1 [(size_t)(n0+row)*NNODE + m0 + col] = sL1[row*17+col];
    L2T[(size_t)(m0+row)*NNODE + n0 + col] = sL2[row*17+col];
}

// ---------------------------------------------------------------------------
// K3: row softmax stats (once per row, not 16x per row) + zero accumulators.
// grid 256 blocks x 256 thr; wave wv handles row g = blk*4+wv (0..1023).
// ---------------------------------------------------------------------------
__global__ __launch_bounds__(256) void k_stats(
    const float* __restrict__ L1, const float* __restrict__ L2T,
    float2* __restrict__ stats, float* __restrict__ temp,
    float* __restrict__ u1, float* __restrict__ v2)
{
    int tid = threadIdx.x;
    int g0 = blockIdx.x * 256 + tid;         // zero-fill accumulators
    if (g0 < 16384) temp[g0] = 0.f;
    else if (g0 < 24576) u1[g0 - 16384] = 0.f;
    else if (g0 < 32768) v2[g0 - 24576] = 0.f;

    int wv = tid >> 6, lane = tid & 63;
    int g = blockIdx.x * 4 + wv;             // row id 0..1023
    const float* rw = (g < NNODE) ? (L1 + (size_t)g*NNODE)
                                  : (L2T + (size_t)(g - NNODE)*NNODE);
    float4 a = *(const float4*)(rw + lane*8);
    float4 b = *(const float4*)(rw + lane*8 + 4);
    float mx = fmaxf(fmaxf(fmaxf(a.x,a.y),fmaxf(a.z,a.w)),
                     fmaxf(fmaxf(b.x,b.y),fmaxf(b.z,b.w)));
    #pragma unroll
    for (int o=32; o; o>>=1) mx = fmaxf(mx, __shfl_xor(mx, o, 64));
    float sm = __expf(a.x-mx)+__expf(a.y-mx)+__expf(a.z-mx)+__expf(a.w-mx)
             + __expf(b.x-mx)+__expf(b.y-mx)+__expf(b.z-mx)+__expf(b.w-mx);
    #pragma unroll
    for (int o=32; o; o>>=1) sm += __shfl_xor(sm, o, 64);
    if (lane == 0) { float2 st; st.x = mx; st.y = 1.0f/sm; stats[g] = st; }
}

// ---------------------------------------------------------------------------
// K34: W-chunk build (LDS, XOR-swizzled) + MFMA GEMM + u-fold.
// grid (32 j-tiles, 32 kc chunks of 256, 2 dir) = 2048 blocks (8/CU).
// Results accumulated via f32 atomics into temp[512][32], u1/v2[512][16].
// ---------------------------------------------------------------------------
__global__ __launch_bounds__(256) void k_smx_gemm(
    const float* __restrict__ L1, const float* __restrict__ L2T,
    const u16* __restrict__ adjP, const u16* __restrict__ adjPT,
    const u16* __restrict__ A2T, const u16* __restrict__ B2T,
    const float2* __restrict__ stats,
    float* __restrict__ temp, float* __restrict__ u1, float* __restrict__ v2)
{
    const int j0 = blockIdx.x * 16, kc = blockIdx.y, dir = blockIdx.z;
    const int tid = threadIdx.x;
    const int wv = tid >> 6, lane = tid & 63, l15 = lane & 15, quad = lane >> 4;
    const float* Lbase = dir ? L2T : L1;

    __shared__ alignas(16) u16 Wt[16*256];      // 8KB: W chunk, 16B-slot XOR swizzle
    __shared__ alignas(16) float redb[4][512];  // 8KB: cross-wave MFMA reduce
    __shared__ float2 sst[16];

    if (tid < 16) sst[tid] = stats[dir*NNODE + j0 + tid];
    __syncthreads();

    // ---- phase 1: W-chunk build + u partial (1 m-column per thread) ----
    {
        int j = tid >> 4, cb = tid & 15;
        int m = kc*16 + cb;                   // global m-column
        float2 st = sst[j];
        float s0 = __expf(Lbase[(size_t)(j0+j)*NNODE + m] - st.x) * st.y;

        const uint4* pp = (const uint4*)(adjP + (size_t)(j0+j)*8192 + m*16);
        float av[16]; unpack8(pp[0], av); unpack8(pp[1], av+8);
        u16 wo[16];
        #pragma unroll
        for (int e=0;e<16;e++) wo[e] = f2bf(s0*av[e]);
        #pragma unroll
        for (int q=0;q<2;q++) {
            int sl = (cb*2 + q) ^ (j & 7);    // swizzled 16B slot (32 slots/row)
            *(uint4*)&Wt[j*256 + sl*8] = pack8(wo + q*8);
        }

        const uint4* qq = (const uint4*)(adjPT + (size_t)(j0+j)*8192 + m*16);
        float tv[16]; unpack8(qq[0], tv); unpack8(qq[1], tv+8);
        float ut[16];
        #pragma unroll
        for (int t=0;t<16;t++) ut[t] = s0*tv[t];
        // exchange-and-halve fold over the 16 cb-lanes (xor 1,2,4,8)
        #pragma unroll
        for (int i=0;i<8;i++) {
            float v0 = (lane&1) ? ut[i] : ut[i+8];
            float r0 = __shfl_xor(v0, 1, 64);
            ut[i] = ((lane&1) ? ut[i+8] : ut[i]) + r0;
        }
        #pragma unroll
        for (int i=0;i<4;i++) {
            float v0 = (lane&2) ? ut[i] : ut[i+4];
            float r0 = __shfl_xor(v0, 2, 64);
            ut[i] = ((lane&2) ? ut[i+4] : ut[i]) + r0;
        }
        #pragma unroll
        for (int i=0;i<2;i++) {
            float v0 = (lane&4) ? ut[i] : ut[i+2];
            float r0 = __shfl_xor(v0, 4, 64);
            ut[i] = ((lane&4) ? ut[i+2] : ut[i]) + r0;
        }
        {
            float v0 = (lane&8) ? ut[0] : ut[1];
            float r0 = __shfl_xor(v0, 8, 64);
            ut[0] = ((lane&8) ? ut[1] : ut[0]) + r0;
        }
        int tm = ((cb&1)<<3) | ((cb&2)<<1) | ((cb&4)>>1) | ((cb&8)>>3);
        atomicAdd((dir ? v2 : u1) + (size_t)(j0+j)*TP + tm, ut[0]);
    }
    __syncthreads();

    // ---- phase 2: MFMA [16 j][256 k] x [256 k][32 d]; wave = k-eighth ----
    {
        const u16* Bmat = dir ? B2T : A2T;
        f4 acc0 = {0.f,0.f,0.f,0.f}, acc1 = {0.f,0.f,0.f,0.f};
        #pragma unroll
        for (int st2 = 0; st2 < 2; st2++) {
            int s = wv*2 + st2;               // 0..7
            bf8 afr = *(const bf8*)&Wt[l15*256 + (((s*4 + quad) ^ (l15 & 7)) << 3)];
            bf8 b0 = *(const bf8*)(Bmat + (size_t)(l15)*8192    + kc*256 + s*32 + quad*8);
            bf8 b1 = *(const bf8*)(Bmat + (size_t)(16+l15)*8192 + kc*256 + s*32 + quad*8);
            acc0 = __builtin_amdgcn_mfma_f32_16x16x32_bf16(afr, b0, acc0, 0, 0, 0);
            acc1 = __builtin_amdgcn_mfma_f32_16x16x32_bf16(afr, b1, acc1, 0, 0, 0);
        }
        #pragma unroll
        for (int r = 0; r < 4; r++) {
            redb[wv][      (quad*4+r)*16 + l15] = acc0[r];
            redb[wv][256 + (quad*4+r)*16 + l15] = acc1[r];
        }
    }
    __syncthreads();
    #pragma unroll
    for (int h = 0; h < 2; h++) {
        int o = tid + h*256;                 // 0..511 over (j,d)
        int jj = o >> 5, d = o & 31;
        int idx = (d >> 4)*256 + jj*16 + (d & 15);
        float v = redb[0][idx] + redb[1][idx] + redb[2][idx] + redb[3][idx];
        atomicAdd(&temp[(size_t)(j0 + jj)*DD + d], v);
    }
}

// ---------------------------------------------------------------------------
// K5: self terms (u1·B2T + v2·A2T) + lrelu; temp already complete.
// ---------------------------------------------------------------------------
__global__ __launch_bounds__(256) void k_final(
    const float* __restrict__ temp, const float* __restrict__ u1, const float* __restrict__ v2,
    const u16* __restrict__ A2T, const u16* __restrict__ B2T, float* __restrict__ out)
{
    int base = blockIdx.x * 256 + threadIdx.x;   // 0..16383 over 64 blocks
    int j = base >> 5, d = base & 31;
    float acc = temp[(size_t)j*DD + d];
    const uint4* pb2 = (const uint4*)(B2T + (size_t)d*8192 + j*16);
    const uint4* pa2 = (const uint4*)(A2T + (size_t)d*8192 + j*16);
    float bv[16], avv[16];
    unpack8(pb2[0], bv);  unpack8(pb2[1], bv+8);
    unpack8(pa2[0], avv); unpack8(pa2[1], avv+8);
    #pragma unroll
    for (int t = 0; t < 16; t++)
        acc += u1[(size_t)j*TP + t]*bv[t] + v2[(size_t)j*TP + t]*avv[t];
    out[(size_t)j*DD + d] = fmaxf(acc, 0.2f*acc);
}

// ---------------------------------------------------------------------------
extern "C" void kernel_launch(void* const* d_in, const int* in_sizes, int n_in,
                              void* d_out, int out_size, void* d_ws, size_t ws_size,
                              hipStream_t stream)
{
    (void)in_sizes; (void)n_in; (void)out_size; (void)ws_size;
    const float* x   = (const float*)d_in[0];
    const float* adj = (const float*)d_in[1];
    const float* W1  = (const float*)d_in[2];
    const float* W2  = (const float*)d_in[3];
    const float* W3  = (const float*)d_in[4];

    char* ws = (char*)d_ws;
    u16*   adjP  = (u16*)(ws);                   // 8 MB
    u16*   adjPT = (u16*)(ws + 0x800000);        // 8 MB
    u16*   A1    = (u16*)(ws + 0x1000000);       // 512 KB each
    u16*   B1    = (u16*)(ws + 0x1080000);
    u16*   A2T   = (u16*)(ws + 0x1100000);
    u16*   B2T   = (u16*)(ws + 0x1180000);
    u16*   Qb    = (u16*)(ws + 0x1200000);       // 32 KB
    float* QAd   = (float*)(ws + 0x1210000);
    float* QB    = (float*)(ws + 0x1220000);
    float* L1    = (float*)(ws + 0x1300000);     // 1 MB
    float* L2T   = (float*)(ws + 0x1400000);     // 1 MB
    float* temp  = (float*)(ws + 0x1500000);     // 64 KB accumulator
    float* u1    = (float*)(ws + 0x1510000);     // 32 KB
    float* v2    = (float*)(ws + 0x1520000);     // 32 KB
    float2* stats= (float2*)(ws + 0x1530000);    // 8 KB

    k_prep_adjp<<<768, 256, 0, stream>>>(x, W1, W2, W3, adj,
                                         A1, B1, A2T, B2T, Qb, QAd, QB, adjP, adjPT);
    k_logits<<<dim3(32,32), 256, 0, stream>>>(Qb, A1, B1, adjP, adjPT, QAd, QB, L1, L2T);
    k_stats<<<256, 256, 0, stream>>>(L1, L2T, stats, temp, u1, v2);
    k_smx_gemm<<<dim3(32,32,2), 256, 0, stream>>>(L1, L2T, adjP, adjPT, A2T, B2T,
                                                  stats, temp, u1, v2);
    k_final<<<64, 256, 0, stream>>>(temp, u1, v2, A2T, B2T, (float*)d_out);
}